// Round 1
// baseline (414.323 us; speedup 1.0000x reference)
//
#include <hip/hip_runtime.h>
#include <hip/hip_bf16.h>

// Problem constants
#define B_   8
#define LQ   1024
#define LK   8192
#define D_   256
#define DC   128
#define EPSF 1e-6f

typedef __attribute__((ext_vector_type(8))) short short8;   // 8 bf16 (4 VGPRs)
typedef __attribute__((ext_vector_type(4))) float floatx4;  // 4 fp32 acc

static __device__ __forceinline__ floatx4 mfma16(short8 a, short8 b, floatx4 c) {
    return __builtin_amdgcn_mfma_f32_16x16x32_bf16(a, b, c, 0, 0, 0);
}

// ---------------------------------------------------------------------------
// K1: G = W_up^T @ W_up  (128x128), stored bf16 row-major.
// grid(128), block(128): block = c1, thread = c2.
__global__ void k_G(const float* __restrict__ W, __hip_bfloat16* __restrict__ G) {
    int c1 = blockIdx.x, c2 = threadIdx.x;
    float acc = 0.f;
    for (int d = 0; d < D_; ++d)
        acc += W[d * DC + c1] * W[d * DC + c2];
    G[c1 * DC + c2] = __float2bfloat16(acc);
}

// ---------------------------------------------------------------------------
// K2: q_sq[row] = sum_d q[row,d]^2 (fp32, from raw fp32 q). One wave per row.
__global__ __launch_bounds__(256) void k_qsq(const float* __restrict__ q,
                                             float* __restrict__ q_sq) {
    int row  = blockIdx.x * 4 + (threadIdx.x >> 6);
    int lane = threadIdx.x & 63;
    const float* r = q + (size_t)row * D_;
    float s = 0.f;
    for (int i = lane; i < D_; i += 64) { float v = r[i]; s += v * v; }
    for (int m = 1; m < 64; m <<= 1) s += __shfl_xor(s, m);
    if (lane == 0) q_sq[row] = s;
}

// ---------------------------------------------------------------------------
// K3: q_proj = (q @ W_up) -> bf16 (8192 x 128). MFMA, K=256 in 4 chunks of 64.
// Block = 128 rows, 4 waves x 32 rows. LDS 36.9 KB.
__global__ __launch_bounds__(256) void k_qproj(const float* __restrict__ q,
                                               const float* __restrict__ W,
                                               __hip_bfloat16* __restrict__ qproj) {
    __shared__ __hip_bfloat16 sA[128 * 72];  // q chunk, rows padded to 72 (144 B)
    __shared__ __hip_bfloat16 sB[128 * 72];  // W^T chunk: row=c, col=d_local
    int t = threadIdx.x, lane = t & 63, w = t >> 6;
    int quad = lane >> 4, li = lane & 15;
    int row0 = blockIdx.x * 128;

    floatx4 acc[2][8];
    for (int mt = 0; mt < 2; ++mt)
        for (int nt = 0; nt < 8; ++nt)
            acc[mt][nt] = (floatx4){0.f, 0.f, 0.f, 0.f};

    for (int kc4 = 0; kc4 < 4; ++kc4) {
        // stage q chunk (fp32 -> bf16): 128 rows x 64 cols
        for (int it = 0; it < 8; ++it) {
            int idx = it * 256 + t;            // 2048 float4s
            int r = idx >> 4, pos = idx & 15;
            float4 v = *(const float4*)(q + (size_t)(row0 + r) * D_ + kc4 * 64 + pos * 4);
            __hip_bfloat16* dst = &sA[r * 72 + pos * 4];
            dst[0] = __float2bfloat16(v.x); dst[1] = __float2bfloat16(v.y);
            dst[2] = __float2bfloat16(v.z); dst[3] = __float2bfloat16(v.w);
        }
        // stage W^T chunk: sB[c*72 + dl] = W[(kc4*64+dl)*128 + c]
        for (int it = 0; it < 32; ++it) {
            int e = it * 256 + t;              // 8192 elements
            int dl = e >> 7, c = e & 127;
            sB[c * 72 + dl] = __float2bfloat16(W[(size_t)(kc4 * 64 + dl) * DC + c]);
        }
        __syncthreads();
        short8 af[2][2];
        for (int mt = 0; mt < 2; ++mt)
            for (int ks = 0; ks < 2; ++ks)
                af[mt][ks] = *(const short8*)&sA[(w * 32 + mt * 16 + li) * 72 + ks * 32 + quad * 8];
        for (int nt = 0; nt < 8; ++nt) {
            for (int ks = 0; ks < 2; ++ks) {
                short8 bf = *(const short8*)&sB[(nt * 16 + li) * 72 + ks * 32 + quad * 8];
                acc[0][nt] = mfma16(af[0][ks], bf, acc[0][nt]);
                acc[1][nt] = mfma16(af[1][ks], bf, acc[1][nt]);
            }
        }
        __syncthreads();
    }
    for (int mt = 0; mt < 2; ++mt)
        for (int nt = 0; nt < 8; ++nt)
            for (int r = 0; r < 4; ++r) {
                int row = w * 32 + mt * 16 + quad * 4 + r;
                int c   = nt * 16 + li;
                qproj[(size_t)(row0 + row) * DC + c] = __float2bfloat16(acc[mt][nt][r]);
            }
}

// ---------------------------------------------------------------------------
// K4: dequant int4 codes -> k_c bf16. 4 elements/thread.
__global__ __launch_bounds__(256) void k_dequant(const int* __restrict__ kq,
                                                 const float* __restrict__ kscale,
                                                 const float* __restrict__ kzero,
                                                 __hip_bfloat16* __restrict__ kc) {
    int i = (blockIdx.x * 256 + threadIdx.x) * 4;   // LK*DC*B = 8388608 total
    int4 codes = *(const int4*)(kq + i);
    int c = i & (DC - 1);
    int b = i >> 20;                                 // LK*DC = 2^20
    float4 sc = *(const float4*)(kscale + b * DC + c);
    float4 zp = *(const float4*)(kzero + b * DC + c);
    __hip_bfloat16* o = kc + i;
    o[0] = __float2bfloat16(sc.x * ((float)codes.x - zp.x));
    o[1] = __float2bfloat16(sc.y * ((float)codes.y - zp.y));
    o[2] = __float2bfloat16(sc.z * ((float)codes.z - zp.z));
    o[3] = __float2bfloat16(sc.w * ((float)codes.w - zp.w));
}

// ---------------------------------------------------------------------------
// K5: k_sq[l] = k_c[l,:] @ G @ k_c[l,:]^T  via MFMA (k_c @ G) then row-dot.
// Block = 128 l-rows; 4 waves x 32 rows, each wave covers all 128 c2 columns.
// LDS exactly 64 KB (unpadded; conflicts acceptable — tiny kernel).
__global__ __launch_bounds__(256) void k_ksq(const __hip_bfloat16* __restrict__ kc,
                                             const __hip_bfloat16* __restrict__ G,
                                             float* __restrict__ k_sq) {
    __shared__ __hip_bfloat16 sK[128 * 128];
    __shared__ __hip_bfloat16 sG[128 * 128];
    int t = threadIdx.x, lane = t & 63, w = t >> 6;
    int quad = lane >> 4, li = lane & 15;
    int b = blockIdx.x >> 6, l0 = (blockIdx.x & 63) * 128;
    const uint4* Ks = (const uint4*)(kc + ((size_t)b * LK + l0) * DC);
    const uint4* Gs = (const uint4*)G;
    uint4* dK = (uint4*)sK; uint4* dG = (uint4*)sG;
    for (int it = 0; it < 8; ++it) {
        int idx = it * 256 + t;          // 2048 uint4 per tile
        dK[idx] = Ks[idx];
        dG[idx] = Gs[idx];
    }
    __syncthreads();
    short8 af[2][4];
    for (int mt = 0; mt < 2; ++mt)
        for (int ks = 0; ks < 4; ++ks)
            af[mt][ks] = *(const short8*)&sK[(w * 32 + mt * 16 + li) * DC + ks * 32 + quad * 8];
    float s[2][4] = {{0,0,0,0},{0,0,0,0}};
    for (int nt = 0; nt < 8; ++nt) {
        floatx4 a0 = (floatx4){0.f,0.f,0.f,0.f};
        floatx4 a1 = (floatx4){0.f,0.f,0.f,0.f};
        for (int ks = 0; ks < 4; ++ks) {
            // B[k=c1][n=c2] = G[c2][c1] (G symmetric) -> contiguous along c1
            short8 bf = *(const short8*)&sG[(nt * 16 + li) * DC + ks * 32 + quad * 8];
            a0 = mfma16(af[0][ks], bf, a0);
            a1 = mfma16(af[1][ks], bf, a1);
        }
        int c2 = nt * 16 + li;
        for (int r = 0; r < 4; ++r) {
            int r0 = w * 32 +        quad * 4 + r;
            int r1 = w * 32 + 16 +   quad * 4 + r;
            s[0][r] += a0[r] * __bfloat162float(sK[r0 * DC + c2]);
            s[1][r] += a1[r] * __bfloat162float(sK[r1 * DC + c2]);
        }
    }
    for (int mt = 0; mt < 2; ++mt)
        for (int r = 0; r < 4; ++r) {
            float v = s[mt][r];
            v += __shfl_xor(v, 1); v += __shfl_xor(v, 2);
            v += __shfl_xor(v, 4); v += __shfl_xor(v, 8);
            if (li == 0)
                k_sq[(size_t)b * LK + l0 + w * 32 + mt * 16 + quad * 4 + r] = v;
        }
}

// ---------------------------------------------------------------------------
// K6: main — qk = q_proj @ k_c^T (bf16 MFMA, 128x128 tile, K=128 in 2 chunks),
// fused hyperbolic-distance epilogue, fp32 output. HBM-write-bound.
__global__ __launch_bounds__(256) void k_main(const __hip_bfloat16* __restrict__ qproj,
                                              const __hip_bfloat16* __restrict__ kc,
                                              const float* __restrict__ q_sq,
                                              const float* __restrict__ k_sq,
                                              float* __restrict__ out) {
    __shared__ __hip_bfloat16 sA[128 * 72];
    __shared__ __hip_bfloat16 sB[128 * 72];
    int t = threadIdx.x, lane = t & 63, w = t >> 6;
    int quad = lane >> 4, li = lane & 15;
    int wm = w >> 1, wn = w & 1;
    int n0 = blockIdx.x * 128, m0 = blockIdx.y * 128, b = blockIdx.z;
    const uint4* Ag = (const uint4*)(qproj + ((size_t)b * LQ + m0) * DC);  // 16 u4/row
    const uint4* Bg = (const uint4*)(kc   + ((size_t)b * LK + n0) * DC);
    uint4* dA = (uint4*)sA; uint4* dB = (uint4*)sB;

    floatx4 acc[4][4];
    for (int i = 0; i < 4; ++i)
        for (int j = 0; j < 4; ++j)
            acc[i][j] = (floatx4){0.f, 0.f, 0.f, 0.f};

    for (int h = 0; h < 2; ++h) {          // K halves of 64
        for (int it = 0; it < 4; ++it) {
            int idx = it * 256 + t;        // 1024 u4 per half-tile
            int r = idx >> 3, ch = idx & 7;
            dA[r * 9 + ch] = Ag[r * 16 + h * 8 + ch];
            dB[r * 9 + ch] = Bg[r * 16 + h * 8 + ch];
        }
        __syncthreads();
        for (int ks = 0; ks < 2; ++ks) {
            short8 af[4], bfr[4];
            for (int i = 0; i < 4; ++i) {
                af[i]  = *(const short8*)&sA[(wm * 64 + i * 16 + li) * 72 + ks * 32 + quad * 8];
                bfr[i] = *(const short8*)&sB[(wn * 64 + i * 16 + li) * 72 + ks * 32 + quad * 8];
            }
            for (int i = 0; i < 4; ++i)
                for (int j = 0; j < 4; ++j)
                    acc[i][j] = mfma16(af[i], bfr[j], acc[i][j]);
        }
        __syncthreads();
    }

    // epilogue: dist = arccosh(1 + 2*diff/denom)
    float ksv[4], knv[4];
    for (int j = 0; j < 4; ++j) {
        ksv[j] = k_sq[(size_t)b * LK + n0 + wn * 64 + j * 16 + li];
        knv[j] = 1.f - fminf(ksv[j], 1.f - EPSF);
    }
    for (int i = 0; i < 4; ++i) {
        for (int r = 0; r < 4; ++r) {
            int mrow = m0 + wm * 64 + i * 16 + quad * 4 + r;
            size_t gm = (size_t)b * LQ + mrow;
            float qs  = q_sq[gm];
            float omq = 1.f - fminf(qs, 1.f - EPSF);
            float* orow = out + gm * LK + n0 + wn * 64;
            for (int j = 0; j < 4; ++j) {
                float diff  = fmaxf(qs + ksv[j] - 2.f * acc[i][j][r], 0.f);
                float denom = omq * knv[j] + EPSF;
                float delta = (2.f * diff) / denom;               // x - 1
                float dist  = __logf((1.f + delta) + sqrtf(delta * (delta + 2.f)));
                orow[j * 16 + li] = dist;
            }
        }
    }
}

// ---------------------------------------------------------------------------
extern "C" void kernel_launch(void* const* d_in, const int* in_sizes, int n_in,
                              void* d_out, int out_size, void* d_ws, size_t ws_size,
                              hipStream_t stream) {
    const float* q      = (const float*)d_in[0];
    const int*   kq     = (const int*)d_in[1];
    const float* kscale = (const float*)d_in[2];
    const float* kzero  = (const float*)d_in[3];
    const float* W      = (const float*)d_in[4];
    float* out = (float*)d_out;

    // workspace layout (18.3 MB total)
    char* ws = (char*)d_ws;
    __hip_bfloat16* qproj = (__hip_bfloat16*)(ws);                 // 2,097,152 B
    __hip_bfloat16* kc    = (__hip_bfloat16*)(ws + 2097152);       // 16,777,216 B
    __hip_bfloat16* G     = (__hip_bfloat16*)(ws + 18874368);      //    32,768 B
    float*          q_sq  = (float*)(ws + 18907136);               //    32,768 B
    float*          k_sq  = (float*)(ws + 18939904);               //   262,144 B

    k_G      <<<128, 128, 0, stream>>>(W, G);
    k_qsq    <<<2048, 256, 0, stream>>>(q, q_sq);
    k_qproj  <<<64, 256, 0, stream>>>(q, W, qproj);
    k_dequant<<<8192, 256, 0, stream>>>(kq, kscale, kzero, kc);
    k_ksq    <<<512, 256, 0, stream>>>(kc, G, k_sq);
    dim3 grid(LK / 128, LQ / 128, B_);
    k_main   <<<grid, 256, 0, stream>>>(qproj, kc, q_sq, k_sq, out);
}

// Round 2
// 408.513 us; speedup vs baseline: 1.0142x; 1.0142x over previous
//
#include <hip/hip_runtime.h>
#include <hip/hip_bf16.h>

// Problem constants
#define B_   8
#define LQ   1024
#define LK   8192
#define D_   256
#define DC   128
#define EPSF 1e-6f

typedef __attribute__((ext_vector_type(8))) short short8;   // 8 bf16 (4 VGPRs)
typedef __attribute__((ext_vector_type(4))) float floatx4;  // 4 fp32 acc

static __device__ __forceinline__ floatx4 mfma16(short8 a, short8 b, floatx4 c) {
    return __builtin_amdgcn_mfma_f32_16x16x32_bf16(a, b, c, 0, 0, 0);
}
static __device__ __forceinline__ float fast_rcp(float x)  { return __builtin_amdgcn_rcpf(x); }
static __device__ __forceinline__ float fast_sqrt(float x) { return __builtin_amdgcn_sqrtf(x); }
static __device__ __forceinline__ float fast_ln(float x)   { return 0.69314718056f * __builtin_amdgcn_logf(x); }

// ---------------------------------------------------------------------------
// K1: G = W_up^T @ W_up  (128x128), stored bf16 row-major. Unrolled 8x with
// independent partial accumulators to break the dependent-FMA/load chain.
__global__ void k_G(const float* __restrict__ W, __hip_bfloat16* __restrict__ G) {
    int c1 = blockIdx.x, c2 = threadIdx.x;
    float a0 = 0.f, a1 = 0.f, a2 = 0.f, a3 = 0.f;
#pragma unroll 4
    for (int d = 0; d < D_; d += 4) {
        a0 += W[(d + 0) * DC + c1] * W[(d + 0) * DC + c2];
        a1 += W[(d + 1) * DC + c1] * W[(d + 1) * DC + c2];
        a2 += W[(d + 2) * DC + c1] * W[(d + 2) * DC + c2];
        a3 += W[(d + 3) * DC + c1] * W[(d + 3) * DC + c2];
    }
    G[c1 * DC + c2] = __float2bfloat16((a0 + a1) + (a2 + a3));
}

// ---------------------------------------------------------------------------
// K2: q_sq[row] = sum_d q[row,d]^2. One wave per row, one float4 per lane.
__global__ __launch_bounds__(256) void k_qsq(const float* __restrict__ q,
                                             float* __restrict__ q_sq) {
    int row  = blockIdx.x * 4 + (threadIdx.x >> 6);
    int lane = threadIdx.x & 63;
    float4 v = *(const float4*)(q + (size_t)row * D_ + lane * 4);
    float s = v.x * v.x + v.y * v.y + v.z * v.z + v.w * v.w;
    for (int m = 1; m < 64; m <<= 1) s += __shfl_xor(s, m);
    if (lane == 0) q_sq[row] = s;
}

// ---------------------------------------------------------------------------
// K3: q_proj = (q @ W_up) -> bf16 (8192 x 128). 128 blocks x 64-row tiles.
__global__ __launch_bounds__(256) void k_qproj(const float* __restrict__ q,
                                               const float* __restrict__ W,
                                               __hip_bfloat16* __restrict__ qproj) {
    __shared__ __hip_bfloat16 sA[64 * 72];   // q chunk (64 rows x 64 cols)
    __shared__ __hip_bfloat16 sB[128 * 72];  // W^T chunk: row=c, col=d_local
    int t = threadIdx.x, lane = t & 63, w = t >> 6;
    int quad = lane >> 4, li = lane & 15;
    int row0 = blockIdx.x * 64;

    floatx4 acc[8];
#pragma unroll
    for (int nt = 0; nt < 8; ++nt) acc[nt] = (floatx4){0.f, 0.f, 0.f, 0.f};

    for (int kc4 = 0; kc4 < 4; ++kc4) {
        // stage q chunk (fp32 -> bf16): 64 rows x 64 cols = 1024 float4
#pragma unroll
        for (int it = 0; it < 4; ++it) {
            int idx = it * 256 + t;
            int r = idx >> 4, pos = idx & 15;
            float4 v = *(const float4*)(q + (size_t)(row0 + r) * D_ + kc4 * 64 + pos * 4);
            __hip_bfloat16* dst = &sA[r * 72 + pos * 4];
            dst[0] = __float2bfloat16(v.x); dst[1] = __float2bfloat16(v.y);
            dst[2] = __float2bfloat16(v.z); dst[3] = __float2bfloat16(v.w);
        }
        // stage W^T chunk: sB[c*72 + dl] = W[(kc4*64+dl)*128 + c]
#pragma unroll
        for (int it = 0; it < 32; ++it) {
            int e = it * 256 + t;
            int dl = e >> 7, c = e & 127;
            sB[c * 72 + dl] = __float2bfloat16(W[(size_t)(kc4 * 64 + dl) * DC + c]);
        }
        __syncthreads();
        short8 af[2];
#pragma unroll
        for (int ks = 0; ks < 2; ++ks)
            af[ks] = *(const short8*)&sA[(w * 16 + li) * 72 + ks * 32 + quad * 8];
#pragma unroll
        for (int nt = 0; nt < 8; ++nt)
#pragma unroll
            for (int ks = 0; ks < 2; ++ks) {
                short8 bf = *(const short8*)&sB[(nt * 16 + li) * 72 + ks * 32 + quad * 8];
                acc[nt] = mfma16(af[ks], bf, acc[nt]);
            }
        __syncthreads();
    }
#pragma unroll
    for (int nt = 0; nt < 8; ++nt)
#pragma unroll
        for (int r = 0; r < 4; ++r) {
            int row = w * 16 + quad * 4 + r;
            qproj[(size_t)(row0 + row) * DC + nt * 16 + li] = __float2bfloat16(acc[nt][r]);
        }
}

// ---------------------------------------------------------------------------
// K4 (fused dequant + k_sq): dequantize 128 rows of codes -> bf16 (to global
// kc AND LDS), then k_sq[l] = kc[l,:] @ G @ kc[l,:]^T via MFMA + row-dot.
// G read straight from L1/L2 (32 KB, shared by all blocks). sK padded to 132.
__global__ __launch_bounds__(256) void k_dq_ksq(const int* __restrict__ kq,
                                                const float* __restrict__ kscale,
                                                const float* __restrict__ kzero,
                                                const __hip_bfloat16* __restrict__ G,
                                                __hip_bfloat16* __restrict__ kc,
                                                float* __restrict__ k_sq) {
    __shared__ __hip_bfloat16 sK[128 * 132];   // 33.8 KB
    int t = threadIdx.x, lane = t & 63, w = t >> 6;
    int quad = lane >> 4, li = lane & 15;
    int b = blockIdx.x >> 6, l0 = (blockIdx.x & 63) * 128;

    // dequant: 4096 int4-groups; col constant per thread across iterations
    const int4* codes = (const int4*)(kq + ((size_t)b * LK + l0) * DC);
    int col = (t & 31) * 4;
    float4 sc = *(const float4*)(kscale + b * DC + col);
    float4 zp = *(const float4*)(kzero + b * DC + col);
    __hip_bfloat16* kco = kc + ((size_t)b * LK + l0) * DC;
#pragma unroll
    for (int it = 0; it < 16; ++it) {
        int idx = it * 256 + t;            // [0,4096)
        int r = idx >> 5;
        int4 c4 = codes[idx];
        __hip_bfloat16 tmp[4];
        tmp[0] = __float2bfloat16(sc.x * ((float)c4.x - zp.x));
        tmp[1] = __float2bfloat16(sc.y * ((float)c4.y - zp.y));
        tmp[2] = __float2bfloat16(sc.z * ((float)c4.z - zp.z));
        tmp[3] = __float2bfloat16(sc.w * ((float)c4.w - zp.w));
        *(uint2*)&sK[r * 132 + col] = *(const uint2*)tmp;
        *(uint2*)(kco + idx * 4)    = *(const uint2*)tmp;
    }
    __syncthreads();

    short8 af[2][4];
#pragma unroll
    for (int mt = 0; mt < 2; ++mt)
#pragma unroll
        for (int ks = 0; ks < 4; ++ks)
            af[mt][ks] = *(const short8*)&sK[(w * 32 + mt * 16 + li) * 132 + ks * 32 + quad * 8];
    float s[2][4] = {{0, 0, 0, 0}, {0, 0, 0, 0}};
#pragma unroll
    for (int nt = 0; nt < 8; ++nt) {
        floatx4 a0 = (floatx4){0.f, 0.f, 0.f, 0.f};
        floatx4 a1 = (floatx4){0.f, 0.f, 0.f, 0.f};
#pragma unroll
        for (int ks = 0; ks < 4; ++ks) {
            // B[k=c1][n=c2] = G[c2][c1] (G symmetric) — contiguous along c1
            short8 bf = *(const short8*)(G + (size_t)(nt * 16 + li) * DC + ks * 32 + quad * 8);
            a0 = mfma16(af[0][ks], bf, a0);
            a1 = mfma16(af[1][ks], bf, a1);
        }
        int c2 = nt * 16 + li;
#pragma unroll
        for (int r = 0; r < 4; ++r) {
            int r0 = w * 32 +      quad * 4 + r;
            int r1 = w * 32 + 16 + quad * 4 + r;
            s[0][r] += a0[r] * __bfloat162float(sK[r0 * 132 + c2]);
            s[1][r] += a1[r] * __bfloat162float(sK[r1 * 132 + c2]);
        }
    }
#pragma unroll
    for (int mt = 0; mt < 2; ++mt)
#pragma unroll
        for (int r = 0; r < 4; ++r) {
            float v = s[mt][r];
            v += __shfl_xor(v, 1); v += __shfl_xor(v, 2);
            v += __shfl_xor(v, 4); v += __shfl_xor(v, 8);
            if (li == 0)
                k_sq[(size_t)b * LK + l0 + w * 32 + mt * 16 + quad * 4 + r] = v;
        }
}

// ---------------------------------------------------------------------------
// K5: main — qk = q_proj @ k_c^T (128x128 tile, K=128 in 2 pipelined halves),
// fused hyperbolic-distance epilogue with fast rcp/sqrt/log. HBM-write-bound.
__global__ __launch_bounds__(256) void k_main(const __hip_bfloat16* __restrict__ qproj,
                                              const __hip_bfloat16* __restrict__ kc,
                                              const float* __restrict__ q_sq,
                                              const float* __restrict__ k_sq,
                                              float* __restrict__ out) {
    __shared__ __hip_bfloat16 sA[128 * 72];
    __shared__ __hip_bfloat16 sB[128 * 72];
    int t = threadIdx.x, lane = t & 63, w = t >> 6;
    int quad = lane >> 4, li = lane & 15;
    int wm = w >> 1, wn = w & 1;
    int n0 = blockIdx.x * 128, m0 = blockIdx.y * 128, b = blockIdx.z;
    const uint4* Ag = (const uint4*)(qproj + ((size_t)b * LQ + m0) * DC);  // 16 u4/row
    const uint4* Bg = (const uint4*)(kc   + ((size_t)b * LK + n0) * DC);
    uint4* dA = (uint4*)sA; uint4* dB = (uint4*)sB;

    floatx4 acc[4][4];
#pragma unroll
    for (int i = 0; i < 4; ++i)
#pragma unroll
        for (int j = 0; j < 4; ++j)
            acc[i][j] = (floatx4){0.f, 0.f, 0.f, 0.f};

    int r_ = t >> 3, ch_ = t & 7;          // 32 rows x 8 chunks per 256-thread pass
    // ---- load half 0 ----
    uint4 ra[4], rb[4];
#pragma unroll
    for (int it = 0; it < 4; ++it) {
        ra[it] = Ag[(it * 32 + r_) * 16 + ch_];
        rb[it] = Bg[(it * 32 + r_) * 16 + ch_];
    }
#pragma unroll
    for (int it = 0; it < 4; ++it) {
        dA[(it * 32 + r_) * 9 + ch_] = ra[it];
        dB[(it * 32 + r_) * 9 + ch_] = rb[it];
    }
    __syncthreads();
    // ---- prefetch half 1 while computing half 0 ----
#pragma unroll
    for (int it = 0; it < 4; ++it) {
        ra[it] = Ag[(it * 32 + r_) * 16 + 8 + ch_];
        rb[it] = Bg[(it * 32 + r_) * 16 + 8 + ch_];
    }
#pragma unroll
    for (int ks = 0; ks < 2; ++ks) {
        short8 af[4], bfr[4];
#pragma unroll
        for (int i = 0; i < 4; ++i) {
            af[i]  = *(const short8*)&sA[(wm * 64 + i * 16 + li) * 72 + ks * 32 + quad * 8];
            bfr[i] = *(const short8*)&sB[(wn * 64 + i * 16 + li) * 72 + ks * 32 + quad * 8];
        }
#pragma unroll
        for (int i = 0; i < 4; ++i)
#pragma unroll
            for (int j = 0; j < 4; ++j)
                acc[i][j] = mfma16(af[i], bfr[j], acc[i][j]);
    }
    __syncthreads();
#pragma unroll
    for (int it = 0; it < 4; ++it) {
        dA[(it * 32 + r_) * 9 + ch_] = ra[it];
        dB[(it * 32 + r_) * 9 + ch_] = rb[it];
    }
    __syncthreads();
#pragma unroll
    for (int ks = 0; ks < 2; ++ks) {
        short8 af[4], bfr[4];
#pragma unroll
        for (int i = 0; i < 4; ++i) {
            af[i]  = *(const short8*)&sA[(wm * 64 + i * 16 + li) * 72 + ks * 32 + quad * 8];
            bfr[i] = *(const short8*)&sB[(wn * 64 + i * 16 + li) * 72 + ks * 32 + quad * 8];
        }
#pragma unroll
        for (int i = 0; i < 4; ++i)
#pragma unroll
            for (int j = 0; j < 4; ++j)
                acc[i][j] = mfma16(af[i], bfr[j], acc[i][j]);
    }

    // epilogue: dist = arccosh(1 + 2*diff/denom), fast-math intrinsics
    float ksv[4], knv[4];
#pragma unroll
    for (int j = 0; j < 4; ++j) {
        ksv[j] = k_sq[(size_t)b * LK + n0 + wn * 64 + j * 16 + li];
        knv[j] = 1.f - fminf(ksv[j], 1.f - EPSF);
    }
#pragma unroll
    for (int i = 0; i < 4; ++i) {
#pragma unroll
        for (int r = 0; r < 4; ++r) {
            int mrow = m0 + wm * 64 + i * 16 + quad * 4 + r;
            size_t gm = (size_t)b * LQ + mrow;
            float qs  = q_sq[gm];
            float omq = 1.f - fminf(qs, 1.f - EPSF);
            float* orow = out + gm * LK + n0 + wn * 64;
#pragma unroll
            for (int j = 0; j < 4; ++j) {
                float diff  = fmaxf(qs + ksv[j] - 2.f * acc[i][j][r], 0.f);
                float delta = 2.f * diff * fast_rcp(omq * knv[j] + EPSF);
                float sq    = fast_sqrt(delta * (delta + 2.f));
                orow[j * 16 + li] = fast_ln(1.f + delta + sq);
            }
        }
    }
}

// ---------------------------------------------------------------------------
extern "C" void kernel_launch(void* const* d_in, const int* in_sizes, int n_in,
                              void* d_out, int out_size, void* d_ws, size_t ws_size,
                              hipStream_t stream) {
    const float* q      = (const float*)d_in[0];
    const int*   kq     = (const int*)d_in[1];
    const float* kscale = (const float*)d_in[2];
    const float* kzero  = (const float*)d_in[3];
    const float* W      = (const float*)d_in[4];
    float* out = (float*)d_out;

    // workspace layout (19.2 MB total)
    char* ws = (char*)d_ws;
    __hip_bfloat16* qproj = (__hip_bfloat16*)(ws);                 // 2,097,152 B
    __hip_bfloat16* kc    = (__hip_bfloat16*)(ws + 2097152);       // 16,777,216 B
    __hip_bfloat16* G     = (__hip_bfloat16*)(ws + 18874368);      //    32,768 B
    float*          q_sq  = (float*)(ws + 18907136);               //    32,768 B
    float*          k_sq  = (float*)(ws + 18939904);               //   262,144 B

    k_G     <<<128, 128, 0, stream>>>(W, G);
    k_qsq   <<<2048, 256, 0, stream>>>(q, q_sq);
    k_qproj <<<128, 256, 0, stream>>>(q, W, qproj);
    k_dq_ksq<<<512, 256, 0, stream>>>(kq, kscale, kzero, G, kc, k_sq);
    dim3 grid(LK / 128, LQ / 128, B_);
    k_main  <<<grid, 256, 0, stream>>>(qproj, kc, q_sq, k_sq, out);
}